// Round 12
// baseline (62.554 us; speedup 1.0000x reference)
//
#include <hip/hip_runtime.h>
#include <math.h>

#define NEGVF (-1e30f)
#define CTC_T 512
#define CTC_C 256
#define CTC_L 128
#define BLANKC (CTC_C - 1)

typedef float f2 __attribute__((ext_vector_type(2)));

#if __has_builtin(__builtin_amdgcn_exp2f)
__device__ __forceinline__ float fexp2(float x) { return __builtin_amdgcn_exp2f(x); }
#else
__device__ __forceinline__ float fexp2(float x) { return exp2f(x); }
#endif
#if __has_builtin(__builtin_amdgcn_logf)
__device__ __forceinline__ float flog2(float x) { return __builtin_amdgcn_logf(x); }
#else
__device__ __forceinline__ float flog2(float x) { return log2f(x); }
#endif

__device__ __forceinline__ float lae2(float a, float b) {
    float m = fmaxf(a, b);
    float n = fminf(a, b);
    return m + flog2(1.0f + fexp2(n - m));
}

// Whole-wave shift-up-by-1 at VALU speed (lane 0 receives 0).
__device__ __forceinline__ float dpp_shr1_f(float x) {
    return __int_as_float(__builtin_amdgcn_update_dpp(
        0, __float_as_int(x), 0x138, 0xF, 0xF, true));
}
__device__ __forceinline__ int dpp_shr1_i(int x) {
    return __builtin_amdgcn_update_dpp(0, x, 0x138, 0xF, 0xF, true);
}

// ---------------- Phase 1: parallel gather/compaction ----------------
// grid = 8*B blocks x 256 threads. Block (b, chunk): wave w handles rows
// t = chunk*64 + w*16 .. +15. Per row: lane k gathers row[l0_k], row[l1_k]
// -> ws1[(b*512+t)*64+k] (coalesced 8B store); lane 0 writes row[blank] ->
// ws2[b*512+t]. Massive TLP: the divergent-gather TA cost (the r8-r11 wall,
// ~40+ cyc/step when serialized behind one chain) pipelines at full rate.
__global__ __launch_bounds__(256) void ctc_gather(
    const int* __restrict__ y_true,
    const float* __restrict__ y_pred,
    f2* __restrict__ ws1,
    float* __restrict__ ws2)
{
    const int bi    = blockIdx.x >> 3;
    const int chunk = blockIdx.x & 7;
    const int tid = threadIdx.x;
    const int w = tid >> 6, k = tid & 63;

    const int* yt = y_true + (size_t)bi * CTC_L;
    const int l0 = yt[2 * k];
    const int l1 = yt[2 * k + 1];
    const float* __restrict__ yb = y_pred + (size_t)bi * CTC_T * CTC_C;
    const int t0 = chunk * 64 + w * 16;

#pragma unroll 8
    for (int i = 0; i < 16; ++i) {
        int t = t0 + i;
        const float* row = yb + (size_t)t * CTC_C;
        f2 pr;
        pr.x = row[l0];
        pr.y = row[l1];
        ws1[((size_t)bi * CTC_T + t) * 64 + k] = pr;
        if (k == 0) ws2[(size_t)bi * CTC_T + t] = row[BLANKC];
    }
}

// ---------------- Phase 2: serial recursion (r8 skeleton) ----------------
// One wave per batch element. Lane k owns states 4k..4k+3 (+ s=256 on lane
// 63). Linear-domain recursion with per-lane scale E, renorm per 8-step
// body; cross-lane a3 via DPP + ldexp. Emits now come from the COMPACTED
// ws: per step 1 coalesced global_load_dwordx2 (pair) + 1 uniform dword
// (blank) — ~9 TA transactions/step instead of ~40. Triple-buffered
// register staging, immediate offsets, counted vmcnt(32)/body.
__global__ __launch_bounds__(64) void ctc_fwd2(
    const f2* __restrict__ ws1,
    const float* __restrict__ ws2,
    const int* __restrict__ in_len,
    const int* __restrict__ lab_len,
    float* __restrict__ out)
{
    __shared__ float sh[2 * CTC_L + 1];

    const int b = blockIdx.x;
    const int k = threadIdx.x;

    const size_t boff = (size_t)b * CTC_T;
    const uint64_t ws1_u = (uint64_t)(uintptr_t)(ws1 + boff * 64);
    const uint64_t ws2_u = (uint64_t)(uintptr_t)(ws2 + boff);

    int inl = in_len[b];
    if (inl > CTC_T) inl = CTC_T;
    const int nsteps = inl - 1;

    // t=0 init from ws (plain loads, consumed before any asm staging)
    f2 pr0 = ws1[boff * 64 + k];
    float pb0 = ws2[boff];
    float a0 = (k == 0) ? pb0 : 0.0f;
    float a1 = (k == 0) ? pr0.x : 0.0f;
    float a2 = 0.0f, a3 = 0.0f, a4 = 0.0f;
    int   E  = 0;
    float pm3raw = 0.0f;

    // skip flags need neighbor label: recompute from ws? No — labels gone.
    // Instead recover skip flags from y_true via lab pointer passed in ws2
    // tail... (kept simple: recompute from ws is impossible; flags come in
    // through a second path below)
    // NOTE: sk flags are computed in kernel_launch-time-invariant fashion
    // from y_true which we still receive: see sk1f/sk3f params via ws?  —
    // Simplest correct route: ctc_fwd2 also takes y_true.
    (void)0;

    const int v_off8 = k << 3;
    int v_zero = 0;

    f2    bufp[3][8];
    float bufb[3][8];

    uint64_t pairbase = ws1_u + (uint64_t)1 * 512;  // t=1 (records 512B apart)
    uint64_t pbbase   = ws2_u + 4;                  // t=1

#define K2_LOAD2O(dst, rb, OFF) \
    asm volatile("global_load_dwordx2 %0, %1, %2 offset:" OFF \
                 : "=v"(dst) : "v"(v_off8), "s"(rb) : "memory")
#define K2_LOAD1O(dst, rb, OFF) \
    asm volatile("global_load_dword %0, %1, %2 offset:" OFF \
                 : "=v"(dst) : "v"(v_zero), "s"(rb) : "memory")
#define K2_LOAD2(dst, rb) \
    asm volatile("global_load_dwordx2 %0, %1, %2" \
                 : "=v"(dst) : "v"(v_off8), "s"(rb) : "memory")
#define K2_LOAD1(dst, rb) \
    asm volatile("global_load_dword %0, %1, %2" \
                 : "=v"(dst) : "v"(v_zero), "s"(rb) : "memory")

#define STAGE_FAST(stg) { \
    K2_LOAD2O(bufp[stg][0], pairbase, "0");    K2_LOAD1O(bufb[stg][0], pbbase, "0"); \
    K2_LOAD2O(bufp[stg][1], pairbase, "512");  K2_LOAD1O(bufb[stg][1], pbbase, "4"); \
    K2_LOAD2O(bufp[stg][2], pairbase, "1024"); K2_LOAD1O(bufb[stg][2], pbbase, "8"); \
    K2_LOAD2O(bufp[stg][3], pairbase, "1536"); K2_LOAD1O(bufb[stg][3], pbbase, "12"); \
    K2_LOAD2O(bufp[stg][4], pairbase, "2048"); K2_LOAD1O(bufb[stg][4], pbbase, "16"); \
    K2_LOAD2O(bufp[stg][5], pairbase, "2560"); K2_LOAD1O(bufb[stg][5], pbbase, "20"); \
    K2_LOAD2O(bufp[stg][6], pairbase, "3072"); K2_LOAD1O(bufb[stg][6], pbbase, "24"); \
    K2_LOAD2O(bufp[stg][7], pairbase, "3584"); K2_LOAD1O(bufb[stg][7], pbbase, "28"); }

#define STGS(stg, r, t0) { \
    int rr = (t0) + (r); if (rr > nsteps) rr = nsteps; \
    uint64_t rb2 = ws1_u + (uint64_t)rr * 512; \
    uint64_t rb1 = ws2_u + (uint64_t)rr * 4; \
    K2_LOAD2(bufp[stg][r], rb2); \
    K2_LOAD1(bufb[stg][r], rb1); }
#define STAGE_SLOW(stg, t0) { \
    STGS(stg, 0, t0) STGS(stg, 1, t0) STGS(stg, 2, t0) STGS(stg, 3, t0) \
    STGS(stg, 4, t0) STGS(stg, 5, t0) STGS(stg, 6, t0) STGS(stg, 7, t0) }

#define LSTEP(cur, r, dX) { \
    float eb = bufb[cur][r]; \
    float e0 = bufp[cur][r].x; \
    float e1 = bufp[cur][r].y; \
    float pmu = ldexpf(pm3raw, dX); \
    float a3n = fmaf(sk3f, a1, a3 + a2) * e1; \
    pm3raw = dpp_shr1_f(a3n); \
    float a0n = (a0 + pmu) * eb; \
    float a1n = fmaf(sk1f, pmu, a1 + a0) * e0; \
    float a2n = (a2 + a1) * eb; \
    a4 = (a4 + a3) * eb; \
    a0 = a0n; a1 = a1n; a2 = a2n; a3 = a3n; \
}

#define BODY(cur, stg) { \
    int t0s = tbase + 16; \
    if (t0s + 7 <= nsteps) { STAGE_FAST(stg); } \
    else                   { STAGE_SLOW(stg, t0s); } \
    pairbase += 4096; pbbase += 32; \
    int EnbOld = dpp_shr1_i(E); \
    float m = fmaxf(fmaxf(fmaxf(a0, a1), fmaxf(a2, a3)), a4); \
    float mm = m * 0x1p64f; \
    int exm = (__float_as_int(mm) >> 23) & 0xff; \
    bool dead = (exm == 0); \
    int dd = dead ? 0 : (191 - exm); \
    a0 = ldexpf(a0, dd); a1 = ldexpf(a1, dd); a2 = ldexpf(a2, dd); \
    a3 = ldexpf(a3, dd); a4 = ldexpf(a4, dd); \
    E -= dd; \
    int E0 = __builtin_amdgcn_readfirstlane(E); \
    E = dead ? E0 : E; \
    int Enb = dpp_shr1_i(E); \
    int dnb  = Enb - E; \
    int dadj = EnbOld - E; \
    asm volatile("s_waitcnt vmcnt(32)" ::: "memory"); \
    __builtin_amdgcn_sched_barrier(0); \
    if (tbase + 7 <= nsteps) { \
        LSTEP(cur, 0, dadj) LSTEP(cur, 1, dnb) LSTEP(cur, 2, dnb) \
        LSTEP(cur, 3, dnb)  LSTEP(cur, 4, dnb) LSTEP(cur, 5, dnb) \
        LSTEP(cur, 6, dnb)  LSTEP(cur, 7, dnb) \
    } else { \
        int rem = nsteps - tbase; \
        LSTEP(cur, 0, dadj) \
        if (rem > 0) { LSTEP(cur, 1, dnb) } \
        if (rem > 1) { LSTEP(cur, 2, dnb) } \
        if (rem > 2) { LSTEP(cur, 3, dnb) } \
        if (rem > 3) { LSTEP(cur, 4, dnb) } \
        if (rem > 4) { LSTEP(cur, 5, dnb) } \
        if (rem > 5) { LSTEP(cur, 6, dnb) } \
        if (rem > 6) { LSTEP(cur, 7, dnb) } \
    } \
}

    // skip flags (sk1f/sk3f) from labels: ws lacks labels, so ctc_fwd2 is
    // launched with y_true bound through lab_len's neighbor param — see
    // extern launch: we pass y_true as a 6th arg via out+? No: simplest is
    // recomputing here from the y_true pointer snuck in through ws2 tail.
    // CLEANER: y_true passed directly (extra kernel arg).
    float sk1f, sk3f;
    {
        const int* yt = (const int*)lab_len;  // placeholder overwritten below
        (void)yt;
        sk1f = 0.0f; sk3f = 0.0f;  // set for real in the templated body below
    }
    // NOTE: real flags set in ctc_fwd2_impl wrapper — this stub never runs.
    (void)sk1f; (void)sk3f;
    if (false) { int tbase = 1; BODY(0, 2); (void)tbase; }

    // unreachable cleanup for compile completeness
    if (k == 0) out[b] = 0.0f;
    (void)sh;
#undef STAGE_FAST
#undef STGS
#undef STAGE_SLOW
#undef LSTEP
#undef BODY
}

// ---- real phase-2 kernel (with labels for skip flags) ----
__global__ __launch_bounds__(64) void ctc_fwd2b(
    const int* __restrict__ y_true,
    const f2* __restrict__ ws1,
    const float* __restrict__ ws2,
    const int* __restrict__ in_len,
    const int* __restrict__ lab_len,
    float* __restrict__ out)
{
    __shared__ float sh[2 * CTC_L + 1];

    const int b = blockIdx.x;
    const int k = threadIdx.x;

    const size_t boff = (size_t)b * CTC_T;
    const uint64_t ws1_u = (uint64_t)(uintptr_t)(ws1 + boff * 64);
    const uint64_t ws2_u = (uint64_t)(uintptr_t)(ws2 + boff);

    const int* yt = y_true + (size_t)b * CTC_L;
    const int l0 = yt[2 * k];
    const int l1 = yt[2 * k + 1];
    const int lm1 = __shfl_up(l1, 1);
    const float sk1f = ((k > 0) && (l0 != lm1) && (l0 != BLANKC)) ? 1.0f : 0.0f;
    const float sk3f = ((l1 != l0) && (l1 != BLANKC)) ? 1.0f : 0.0f;

    int inl = in_len[b];
    if (inl > CTC_T) inl = CTC_T;
    const int nsteps = inl - 1;

    f2 pr0 = ws1[boff * 64 + k];
    float pb0 = ws2[boff];
    float a0 = (k == 0) ? pb0 : 0.0f;
    float a1 = (k == 0) ? pr0.x : 0.0f;
    float a2 = 0.0f, a3 = 0.0f, a4 = 0.0f;
    int   E  = 0;
    float pm3raw = 0.0f;

    const int v_off8 = k << 3;
    int v_zero = 0;

    f2    bufp[3][8];
    float bufb[3][8];

    uint64_t pairbase = ws1_u + 512;   // t=1 (records 512B apart)
    uint64_t pbbase   = ws2_u + 4;     // t=1

#define K2_LOAD2O(dst, rb, OFF) \
    asm volatile("global_load_dwordx2 %0, %1, %2 offset:" OFF \
                 : "=v"(dst) : "v"(v_off8), "s"(rb) : "memory")
#define K2_LOAD1O(dst, rb, OFF) \
    asm volatile("global_load_dword %0, %1, %2 offset:" OFF \
                 : "=v"(dst) : "v"(v_zero), "s"(rb) : "memory")
#define K2_LOAD2(dst, rb) \
    asm volatile("global_load_dwordx2 %0, %1, %2" \
                 : "=v"(dst) : "v"(v_off8), "s"(rb) : "memory")
#define K2_LOAD1(dst, rb) \
    asm volatile("global_load_dword %0, %1, %2" \
                 : "=v"(dst) : "v"(v_zero), "s"(rb) : "memory")

#define STAGE_FAST(stg) { \
    K2_LOAD2O(bufp[stg][0], pairbase, "0");    K2_LOAD1O(bufb[stg][0], pbbase, "0"); \
    K2_LOAD2O(bufp[stg][1], pairbase, "512");  K2_LOAD1O(bufb[stg][1], pbbase, "4"); \
    K2_LOAD2O(bufp[stg][2], pairbase, "1024"); K2_LOAD1O(bufb[stg][2], pbbase, "8"); \
    K2_LOAD2O(bufp[stg][3], pairbase, "1536"); K2_LOAD1O(bufb[stg][3], pbbase, "12"); \
    K2_LOAD2O(bufp[stg][4], pairbase, "2048"); K2_LOAD1O(bufb[stg][4], pbbase, "16"); \
    K2_LOAD2O(bufp[stg][5], pairbase, "2560"); K2_LOAD1O(bufb[stg][5], pbbase, "20"); \
    K2_LOAD2O(bufp[stg][6], pairbase, "3072"); K2_LOAD1O(bufb[stg][6], pbbase, "24"); \
    K2_LOAD2O(bufp[stg][7], pairbase, "3584"); K2_LOAD1O(bufb[stg][7], pbbase, "28"); }

#define STGS(stg, r, t0) { \
    int rr = (t0) + (r); if (rr > nsteps) rr = nsteps; \
    uint64_t rb2 = ws1_u + (uint64_t)rr * 512; \
    uint64_t rb1 = ws2_u + (uint64_t)rr * 4; \
    K2_LOAD2(bufp[stg][r], rb2); \
    K2_LOAD1(bufb[stg][r], rb1); }
#define STAGE_SLOW(stg, t0) { \
    STGS(stg, 0, t0) STGS(stg, 1, t0) STGS(stg, 2, t0) STGS(stg, 3, t0) \
    STGS(stg, 4, t0) STGS(stg, 5, t0) STGS(stg, 6, t0) STGS(stg, 7, t0) }

#define LSTEP(cur, r, dX) { \
    float eb = bufb[cur][r]; \
    float e0 = bufp[cur][r].x; \
    float e1 = bufp[cur][r].y; \
    float pmu = ldexpf(pm3raw, dX); \
    float a3n = fmaf(sk3f, a1, a3 + a2) * e1; \
    pm3raw = dpp_shr1_f(a3n); \
    float a0n = (a0 + pmu) * eb; \
    float a1n = fmaf(sk1f, pmu, a1 + a0) * e0; \
    float a2n = (a2 + a1) * eb; \
    a4 = (a4 + a3) * eb; \
    a0 = a0n; a1 = a1n; a2 = a2n; a3 = a3n; \
}

#define BODY(cur, stg) { \
    int t0s = tbase + 16; \
    if (t0s + 7 <= nsteps) { STAGE_FAST(stg); } \
    else                   { STAGE_SLOW(stg, t0s); } \
    pairbase += 4096; pbbase += 32; \
    int EnbOld = dpp_shr1_i(E); \
    float m = fmaxf(fmaxf(fmaxf(a0, a1), fmaxf(a2, a3)), a4); \
    float mm = m * 0x1p64f; \
    int exm = (__float_as_int(mm) >> 23) & 0xff; \
    bool dead = (exm == 0); \
    int dd = dead ? 0 : (191 - exm); \
    a0 = ldexpf(a0, dd); a1 = ldexpf(a1, dd); a2 = ldexpf(a2, dd); \
    a3 = ldexpf(a3, dd); a4 = ldexpf(a4, dd); \
    E -= dd; \
    int E0 = __builtin_amdgcn_readfirstlane(E); \
    E = dead ? E0 : E; \
    int Enb = dpp_shr1_i(E); \
    int dnb  = Enb - E; \
    int dadj = EnbOld - E; \
    asm volatile("s_waitcnt vmcnt(32)" ::: "memory"); \
    __builtin_amdgcn_sched_barrier(0); \
    if (tbase + 7 <= nsteps) { \
        LSTEP(cur, 0, dadj) LSTEP(cur, 1, dnb) LSTEP(cur, 2, dnb) \
        LSTEP(cur, 3, dnb)  LSTEP(cur, 4, dnb) LSTEP(cur, 5, dnb) \
        LSTEP(cur, 6, dnb)  LSTEP(cur, 7, dnb) \
    } else { \
        int rem = nsteps - tbase; \
        LSTEP(cur, 0, dadj) \
        if (rem > 0) { LSTEP(cur, 1, dnb) } \
        if (rem > 1) { LSTEP(cur, 2, dnb) } \
        if (rem > 2) { LSTEP(cur, 3, dnb) } \
        if (rem > 3) { LSTEP(cur, 4, dnb) } \
        if (rem > 4) { LSTEP(cur, 5, dnb) } \
        if (rem > 5) { LSTEP(cur, 6, dnb) } \
        if (rem > 6) { LSTEP(cur, 7, dnb) } \
    } \
}

    const int nb2 = (nsteps > 0) ? ((nsteps + 7) >> 3) : 0;
    int tbase = 1;

    if (nb2 >= 1) {
        __builtin_amdgcn_sched_barrier(0);
        if (8 <= nsteps)  { STAGE_FAST(0); } else { STAGE_SLOW(0, 1); }
        pairbase += 4096; pbbase += 32;
        if (16 <= nsteps) { STAGE_FAST(1); } else { STAGE_SLOW(1, 9); }
        pairbase += 4096; pbbase += 32;
        int j = 0;
        for (;;) {
            BODY(0, 2); tbase += 8; if (++j >= nb2) break;
            BODY(1, 0); tbase += 8; if (++j >= nb2) break;
            BODY(2, 1); tbase += 8; if (++j >= nb2) break;
        }
    }

    float l0v = fmaxf(flog2(a0) + (float)E, NEGVF);
    float l1v = fmaxf(flog2(a1) + (float)E, NEGVF);
    float l2v = fmaxf(flog2(a2) + (float)E, NEGVF);
    float l3v = fmaxf(flog2(a3) + (float)E, NEGVF);
    float l4v = fmaxf(flog2(a4) + (float)E, NEGVF);

    sh[4 * k + 0] = l0v;
    sh[4 * k + 1] = l1v;
    sh[4 * k + 2] = l2v;
    sh[4 * k + 3] = l3v;
    if (k == 63) sh[256] = l4v;
    __syncthreads();
    if (k == 0) {
        int ll = lab_len[b];
        if (ll < 1) ll = 1;
        if (ll > CTC_L) ll = CTC_L;
        float ea = sh[2 * ll - 1];
        float eb = sh[2 * ll];
        int cnt = 1 + (nsteps > 0 ? nsteps : 0);
        const float LSE2 = flog2(1.0f + (float)CTC_C * 1e-7f);
        out[b] = -0.69314718055994530942f * (lae2(ea, eb) - (float)cnt * LSE2);
    }
#undef K2_LOAD2O
#undef K2_LOAD1O
#undef K2_LOAD2
#undef K2_LOAD1
#undef STAGE_FAST
#undef STGS
#undef STAGE_SLOW
#undef LSTEP
#undef BODY
}

extern "C" void kernel_launch(void* const* d_in, const int* in_sizes, int n_in,
                              void* d_out, int out_size, void* d_ws, size_t ws_size,
                              hipStream_t stream) {
    (void)n_in; (void)out_size;
    const int* y_true = (const int*)d_in[0];
    const float* y_pred = (const float*)d_in[1];
    const int* in_len = (const int*)d_in[2];
    const int* lab_len = (const int*)d_in[3];
    float* out = (float*)d_out;
    const int B = in_sizes[2];

    const size_t ws1_bytes = (size_t)B * CTC_T * 64 * sizeof(f2);   // 8B/lane
    const size_t ws2_bytes = (size_t)B * CTC_T * sizeof(float);
    f2* ws1 = (f2*)d_ws;
    float* ws2 = (float*)((char*)d_ws + ws1_bytes);

    if (ws_size >= ws1_bytes + ws2_bytes) {
        ctc_gather<<<B * 8, 256, 0, stream>>>(y_true, y_pred, ws1, ws2);
        ctc_fwd2b<<<B, 64, 0, stream>>>(y_true, ws1, ws2, in_len, lab_len, out);
    } else {
        // Should not happen for this workload; ws too small -> phase-2 only
        // path unavailable. Launch gather into nothing is invalid, so fall
        // back to a degenerate correct path: run phase 2 reading a ws we
        // build in out? Not possible — instead rely on harness providing
        // adequate ws. As a last resort, write zeros (prevents UB).
        hipMemsetAsync(out, 0, (size_t)B * sizeof(float), stream);
    }
}

// Round 13
// 40.149 us; speedup vs baseline: 1.5581x; 1.5581x over previous
//
#include <hip/hip_runtime.h>
#include <math.h>

#define NEGVF (-1e30f)
#define CTC_T 512
#define CTC_C 256
#define CTC_L 128
#define BLANKC (CTC_C - 1)

typedef float f4 __attribute__((ext_vector_type(4)));

#if __has_builtin(__builtin_amdgcn_exp2f)
__device__ __forceinline__ float fexp2(float x) { return __builtin_amdgcn_exp2f(x); }
#else
__device__ __forceinline__ float fexp2(float x) { return exp2f(x); }
#endif
#if __has_builtin(__builtin_amdgcn_logf)
__device__ __forceinline__ float flog2(float x) { return __builtin_amdgcn_logf(x); }
#else
__device__ __forceinline__ float flog2(float x) { return log2f(x); }
#endif

__device__ __forceinline__ float lae2(float a, float b) {
    float m = fmaxf(a, b);
    float n = fminf(a, b);
    return m + flog2(1.0f + fexp2(n - m));
}

// Whole-wave shift-up-by-1 at VALU speed (lane 0 receives 0).
__device__ __forceinline__ float dpp_shr1_f(float x) {
    return __int_as_float(__builtin_amdgcn_update_dpp(
        0, __float_as_int(x), 0x138, 0xF, 0xF, true));
}
__device__ __forceinline__ int dpp_shr1_i(int x) {
    return __builtin_amdgcn_update_dpp(0, x, 0x138, 0xF, 0xF, true);
}

// 2 waves per block, 1 block per batch element.
//   wave 0 = consumer: linear-domain CTC recursion; per step 3 ds_reads
//            (blank = uniform broadcast, p0/p1 divergent ~2-4-way) from the
//            LDS ring + 14 VALU. NO divergent global loads anywhere.
//   wave 1 = producer: per period, 8 COALESCED global_load_dwordx4 (one per
//            row, whole 1 KB row; TA-cheap) for body jj+1, vmcnt(8) -> body
//            jj's rows arrived in regs, ds_write_b128 them to ring slot jj&3.
// Periods jj = 0..nb2+1, one s_barrier per period (equal count both waves).
// Slot audit, period jj: producer writes jj&3; consumer reads (jj-2)&3 and
// primes (jj-1)&3 (written period jj-1, barrier-separated). All distinct mod 4.
__global__ __launch_bounds__(128) void ctc_fwd_kernel(
    const int* __restrict__ y_true,    // [B, L]
    const float* __restrict__ y_pred,  // [B, T, C]
    const int* __restrict__ in_len,    // [B]
    const int* __restrict__ lab_len,   // [B]
    float* __restrict__ out)           // [B]
{
    __shared__ float ring[4][8][CTC_C];   // 32 KB staging ring
    __shared__ float sh[2 * CTC_L + 1];

    const int b   = blockIdx.x;
    const int tid = threadIdx.x;
    const int wid = tid >> 6;   // 0..1
    const int k   = tid & 63;

    const float* __restrict__ ybase = y_pred + (size_t)b * CTC_T * CTC_C;
    const uint64_t ybase_u = (uint64_t)(uintptr_t)ybase;
    const int* __restrict__ yt = y_true + (size_t)b * CTC_L;

    const int l0 = yt[2 * k];
    const int l1 = yt[2 * k + 1];
    const int lm1 = __shfl_up(l1, 1);  // wave-local (same in both waves)
    const float sk1f = ((k > 0) && (l0 != lm1) && (l0 != BLANKC)) ? 1.0f : 0.0f;
    const float sk3f = ((l1 != l0) && (l1 != BLANKC)) ? 1.0f : 0.0f;

    int inl = in_len[b];
    if (inl > CTC_T) inl = CTC_T;
    const int nsteps = inl - 1;
    const int nb2 = (nsteps > 0) ? ((nsteps + 7) >> 3) : 0;

    // t = 0 init (linear domain); used by consumer only
    float pb0 = ybase[BLANKC];
    float p00 = ybase[l0];
    float a0 = (k == 0) ? pb0 : 0.0f;
    float a1 = (k == 0) ? p00 : 0.0f;
    float a2 = 0.0f, a3 = 0.0f, a4 = 0.0f;
    int   E  = 0;
    float pm3raw = 0.0f;

    const int v_off4 = k << 4;  // coalesced: lane k -> bytes [16k,16k+16)

#define LOADR(dst, rb) \
    asm volatile("global_load_dwordx4 %0, %1, %2" \
                 : "=v"(dst) : "v"(v_off4), "s"(rb) : "memory")

    if (nb2 >= 1) {
        if (wid == 0) {
            // ---------------- consumer ----------------
            float pbC = 0, p0C = 0, p1C = 0, pbM = 0, p0M = 0, p1M = 0;
            float pbN = 0, p0N = 0, p1N = 0;

#define RD(S_, r_, A, Bv, Cv) { \
    const float* rp_ = &ring[S_][r_][0]; \
    A  = rp_[BLANKC]; \
    Bv = rp_[l0]; \
    Cv = rp_[l1]; }

#define CARITH(dX) { \
    float pmu = ldexpf(pm3raw, dX); \
    float a3n = fmaf(sk3f, a1, a3 + a2) * p1C; \
    pm3raw = dpp_shr1_f(a3n); \
    float a0n = (a0 + pmu) * pbC; \
    float a1n = fmaf(sk1f, pmu, a1 + a0) * p0C; \
    float a2n = (a2 + a1) * pbC; \
    a4 = (a4 + a3) * pbC; \
    a0 = a0n; a1 = a1n; a2 = a2n; a3 = a3n; }

#define ROT2 { pbC = pbM; p0C = p0M; p1C = p1M; pbM = pbN; p0M = p0N; p1M = p1N; }
#define ROT1 { pbC = pbM; p0C = p0M; p1C = p1M; }

            for (int jj = 0; jj < nb2 + 2; ++jj) {
                int cj = jj - 2;
                if (cj >= 0) {
                    int tbase = 1 + 8 * cj;
                    int rem = nsteps - tbase;
                    int S = cj & 3;
                    // per-body renorm
                    int EnbOld = dpp_shr1_i(E);
                    float m = fmaxf(fmaxf(fmaxf(a0, a1), fmaxf(a2, a3)), a4);
                    float mm = m * 0x1p64f;
                    int exm = (__float_as_int(mm) >> 23) & 0xff;
                    bool dead = (exm == 0);
                    int dd = dead ? 0 : (191 - exm);
                    a0 = ldexpf(a0, dd); a1 = ldexpf(a1, dd); a2 = ldexpf(a2, dd);
                    a3 = ldexpf(a3, dd); a4 = ldexpf(a4, dd);
                    E -= dd;
                    int E0 = __builtin_amdgcn_readfirstlane(E);
                    E = dead ? E0 : E;
                    int Enb = dpp_shr1_i(E);
                    int dnb  = Enb - E;
                    int dadj = EnbOld - E;
                    // 8 steps, ds_reads prefetched 2 ahead within the slot
                    { RD(S, 2, pbN, p0N, p1N); CARITH(dadj); ROT2 }
                    if (rem > 0) { RD(S, 3, pbN, p0N, p1N); CARITH(dnb); ROT2 }
                    if (rem > 1) { RD(S, 4, pbN, p0N, p1N); CARITH(dnb); ROT2 }
                    if (rem > 2) { RD(S, 5, pbN, p0N, p1N); CARITH(dnb); ROT2 }
                    if (rem > 3) { RD(S, 6, pbN, p0N, p1N); CARITH(dnb); ROT2 }
                    if (rem > 4) { RD(S, 7, pbN, p0N, p1N); CARITH(dnb); ROT2 }
                    if (rem > 5) { CARITH(dnb); ROT1 }
                    if (rem > 6) { CARITH(dnb); }
                }
                int nj = jj - 1;  // prime body nj's rows 0,1 (slot written jj-1)
                if (nj >= 0 && nj < nb2) {
                    int S2 = nj & 3;
                    RD(S2, 0, pbC, p0C, p1C);
                    RD(S2, 1, pbM, p0M, p1M);
                }
                __builtin_amdgcn_s_barrier();
                asm volatile("" ::: "memory");
            }
#undef RD
#undef CARITH
#undef ROT2
#undef ROT1
        } else {
            // ---------------- producer ----------------
            f4 bufA[8], bufB[8];

#define PISSUE(buf, bi_) { \
    int t0 = 1 + 8 * (bi_); \
    { int rr = t0 + 0; if (rr > nsteps) rr = nsteps; \
      uint64_t rb = ybase_u + (uint64_t)rr * 1024; LOADR(buf[0], rb); } \
    { int rr = t0 + 1; if (rr > nsteps) rr = nsteps; \
      uint64_t rb = ybase_u + (uint64_t)rr * 1024; LOADR(buf[1], rb); } \
    { int rr = t0 + 2; if (rr > nsteps) rr = nsteps; \
      uint64_t rb = ybase_u + (uint64_t)rr * 1024; LOADR(buf[2], rb); } \
    { int rr = t0 + 3; if (rr > nsteps) rr = nsteps; \
      uint64_t rb = ybase_u + (uint64_t)rr * 1024; LOADR(buf[3], rb); } \
    { int rr = t0 + 4; if (rr > nsteps) rr = nsteps; \
      uint64_t rb = ybase_u + (uint64_t)rr * 1024; LOADR(buf[4], rb); } \
    { int rr = t0 + 5; if (rr > nsteps) rr = nsteps; \
      uint64_t rb = ybase_u + (uint64_t)rr * 1024; LOADR(buf[5], rb); } \
    { int rr = t0 + 6; if (rr > nsteps) rr = nsteps; \
      uint64_t rb = ybase_u + (uint64_t)rr * 1024; LOADR(buf[6], rb); } \
    { int rr = t0 + 7; if (rr > nsteps) rr = nsteps; \
      uint64_t rb = ybase_u + (uint64_t)rr * 1024; LOADR(buf[7], rb); } }

#define PWRITE(buf, S_) { \
    ((f4*)&ring[S_][0][0])[k] = buf[0]; \
    ((f4*)&ring[S_][1][0])[k] = buf[1]; \
    ((f4*)&ring[S_][2][0])[k] = buf[2]; \
    ((f4*)&ring[S_][3][0])[k] = buf[3]; \
    ((f4*)&ring[S_][4][0])[k] = buf[4]; \
    ((f4*)&ring[S_][5][0])[k] = buf[5]; \
    ((f4*)&ring[S_][6][0])[k] = buf[6]; \
    ((f4*)&ring[S_][7][0])[k] = buf[7]; }

// one producer period: body jj lives in `cur`, issue body jj+1 into `nxt`
#define PPERIOD(cur, nxt) { \
    bool iss = (jj + 1 < nb2); \
    if (iss) { PISSUE(nxt, jj + 1); } \
    if (jj < nb2) { \
        if (iss) { asm volatile("s_waitcnt vmcnt(8)" ::: "memory"); } \
        else     { asm volatile("s_waitcnt vmcnt(0)" ::: "memory"); } \
        __builtin_amdgcn_sched_barrier(0); \
        int S = jj & 3; \
        PWRITE(cur, S); \
        asm volatile("s_waitcnt lgkmcnt(0)" ::: "memory"); \
    } \
    __builtin_amdgcn_s_barrier(); \
    ++jj; }

            int jj = 0;
            __builtin_amdgcn_sched_barrier(0);  // fence init loads from asm
            PISSUE(bufA, 0);
            for (;;) {
                PPERIOD(bufA, bufB);
                if (jj >= nb2 + 2) break;
                PPERIOD(bufB, bufA);
                if (jj >= nb2 + 2) break;
            }
#undef PISSUE
#undef PWRITE
#undef PPERIOD
        }
    }

    // convert to absolute log2 (clamp so dead states act like NEG, not -inf)
    float l0v = fmaxf(flog2(a0) + (float)E, NEGVF);
    float l1v = fmaxf(flog2(a1) + (float)E, NEGVF);
    float l2v = fmaxf(flog2(a2) + (float)E, NEGVF);
    float l3v = fmaxf(flog2(a3) + (float)E, NEGVF);
    float l4v = fmaxf(flog2(a4) + (float)E, NEGVF);

    if (wid == 0) {
        sh[4 * k + 0] = l0v;
        sh[4 * k + 1] = l1v;
        sh[4 * k + 2] = l2v;
        sh[4 * k + 3] = l3v;
        if (k == 63) sh[256] = l4v;
    }
    __syncthreads();
    if (tid == 0) {
        int ll = lab_len[b];
        if (ll < 1) ll = 1;
        if (ll > CTC_L) ll = CTC_L;
        float ea = sh[2 * ll - 1];
        float eb = sh[2 * ll];
        int cnt = 1 + (nsteps > 0 ? nsteps : 0);
        const float LSE2 = flog2(1.0f + (float)CTC_C * 1e-7f);
        out[b] = -0.69314718055994530942f * (lae2(ea, eb) - (float)cnt * LSE2);
    }
#undef LOADR
}

extern "C" void kernel_launch(void* const* d_in, const int* in_sizes, int n_in,
                              void* d_out, int out_size, void* d_ws, size_t ws_size,
                              hipStream_t stream) {
    (void)n_in; (void)d_ws; (void)ws_size; (void)out_size;
    const int* y_true = (const int*)d_in[0];
    const float* y_pred = (const float*)d_in[1];
    const int* in_len = (const int*)d_in[2];
    const int* lab_len = (const int*)d_in[3];
    float* out = (float*)d_out;
    const int B = in_sizes[2];  // input_length has B elements
    ctc_fwd_kernel<<<B, 128, 0, stream>>>(y_true, y_pred, in_len, lab_len, out);
}